// Round 4
// baseline (679.699 us; speedup 1.0000x reference)
//
#include <hip/hip_runtime.h>

#define D_MODEL 512
#define NH 8
#define HD_ 64
#define NUM_I 3
#define B_ 4
#define NSEQ 8192
#define SSEQ 4096

typedef __attribute__((ext_vector_type(8))) short short8;
typedef __attribute__((ext_vector_type(4))) float floatx4;

// workspace layout (float-element offsets)
static constexpr size_t Q_OFF    = 0;           // qb bf16 (8,388,608 float slots)
static constexpr size_t Q2_OFF   = 8388608;     // q2b bf16 (8,388,608)
static constexpr size_t KT_OFF   = 16777216;    // kT bf16 (4,194,304)
static constexpr size_t VT_OFF   = 20971520;    // vT bf16 (4,194,304)
static constexpr size_t WB_OFF   = 25165824;    // weights bf16 (1,048,576)
static constexpr size_t KV_OFF   = 26214400;    // kv fp32 (393,216)
static constexpr size_t KS_OFF   = 26607616;    // ksum fp32 (6,144)
static constexpr size_t KVB_OFF  = 26613760;    // kv bf16 (98,304 float slots)
static constexpr size_t FLAG_OFF = 26712064;    // 1 int

__device__ __forceinline__ float bf2f(unsigned short u) {
    union { unsigned i; float f; } v; v.i = ((unsigned)u) << 16; return v.f;
}
__device__ __forceinline__ unsigned short f2bf(float f) {
    union { float f; unsigned i; } v; v.f = f;
    unsigned r = v.i + 0x7fffu + ((v.i >> 16) & 1u);
    return (unsigned short)(r >> 16);
}
__device__ __forceinline__ void gld16(const void* g, void* l) {
    __builtin_amdgcn_global_load_lds((const __attribute__((address_space(1))) void*)g,
                                     (__attribute__((address_space(3))) void*)l, 16, 0, 0);
}
__device__ __forceinline__ short8 cvt8(const float4& a, const float4& b) {
    short8 r;
    r[0] = (short)f2bf(a.x); r[1] = (short)f2bf(a.y);
    r[2] = (short)f2bf(a.z); r[3] = (short)f2bf(a.w);
    r[4] = (short)f2bf(b.x); r[5] = (short)f2bf(b.y);
    r[6] = (short)f2bf(b.z); r[7] = (short)f2bf(b.w);
    return r;
}

// Detect mask storage: int32 words (0/1) vs packed numpy bool bytes.
__global__ void mask_mode_kernel(const int* __restrict__ m, int* __restrict__ flag)
{
    __shared__ int any;
    if (threadIdx.x == 0) any = 0;
    __syncthreads();
    const unsigned v = (unsigned)m[threadIdx.x];
    if (v > 1u) atomicOr(&any, 1);
    __syncthreads();
    if (threadIdx.x == 0) *flag = any;
}

// fp32 -> bf16 pack, 8 elems/thread (weights + kv only now)
__global__ __launch_bounds__(256)
void f2bf_kernel(const float* __restrict__ in, unsigned short* __restrict__ out, int n8)
{
    const int i = blockIdx.x * 256 + threadIdx.x;
    if (i >= n8) return;
    const float4 a = ((const float4*)in)[2*i];
    const float4 b = ((const float4*)in)[2*i + 1];
    ((short8*)out)[i] = cvt8(a, b);
}

// Barrier-free GEMM: C[m][n] = sum_k A[m][k]*W[n][k] + bias[n].
// Per block: 4 waves x (64 rows x 64 cols), W 64-col strip resident in LDS (loaded once).
// A-frags loaded DIRECTLY from global (k-contiguous), depth-2 prefetch, no K-loop barriers.
// EPI: 0 none, 1 softmax per 64-col head, 2 softmax+row-mask.
// OUT: 0 fp32 row-major, 1 bf16 row-major, 2 bf16 transposed -> Cv[(b*NH+h)*64+d][SSEQ]
// AFP32: A is fp32 (convert in-register) else bf16.
template<int EPI, int OUT, bool AFP32>
__global__ __launch_bounds__(256)
void proj2(const void* __restrict__ Av, const unsigned short* __restrict__ W,
           const float* __restrict__ bias, const int* __restrict__ mask,
           const int* __restrict__ maskmode, void* __restrict__ Cv)
{
    __shared__ short Ws[64 * 520];       // padded stride: 520 shorts -> 2-way-free b128 reads
    const int tid = threadIdx.x;
    const int wid = tid >> 6, lane = tid & 63;
    const int l15 = lane & 15, lq = lane >> 4;
    const int m0w = blockIdx.x * 256 + wid * 64;   // wave's 64 rows
    const int n0  = blockIdx.y * 64;               // block's 64-col strip (= one head)

    // stage W strip once: row r of strip = W[n0+r][0..511] -> Ws[r*520 .. +512]
#pragma unroll
    for (int j = 0; j < 16; ++j) {
        const int row = wid * 16 + j;
        gld16(W + (size_t)(n0 + row) * D_MODEL + lane * 8, Ws + row * 520);
    }
    __syncthreads();   // single barrier; K-loop below is barrier-free

    floatx4 acc[4][4] = {};
    const float*          Af = (const float*)Av;
    const unsigned short* Ab = (const unsigned short*)Av;

    size_t abase[4];
#pragma unroll
    for (int mt = 0; mt < 4; ++mt)
        abase[mt] = (size_t)(m0w + mt * 16 + l15) * D_MODEL + lq * 8;

    short8 afc[4];
    if (AFP32) {
        float4 buf[2][4][2];
#pragma unroll
        for (int mt = 0; mt < 4; ++mt) {
            const float4* p0 = (const float4*)(Af + abase[mt]);
            buf[0][mt][0] = p0[0]; buf[0][mt][1] = p0[1];
            const float4* p1 = (const float4*)(Af + abase[mt] + 32);
            buf[1][mt][0] = p1[0]; buf[1][mt][1] = p1[1];
        }
#pragma unroll
        for (int mt = 0; mt < 4; ++mt) afc[mt] = cvt8(buf[0][mt][0], buf[0][mt][1]);
#pragma unroll
        for (int kk = 0; kk < 16; ++kk) {
            const int k0 = kk * 32;
            if (kk < 14) {
#pragma unroll
                for (int mt = 0; mt < 4; ++mt) {
                    const float4* p = (const float4*)(Af + abase[mt] + k0 + 64);
                    buf[kk & 1][mt][0] = p[0]; buf[kk & 1][mt][1] = p[1];
                }
            }
            short8 bfr[4];
#pragma unroll
            for (int nt = 0; nt < 4; ++nt)
                bfr[nt] = *(const short8*)&Ws[(nt * 16 + l15) * 520 + k0 + lq * 8];
#pragma unroll
            for (int mt = 0; mt < 4; ++mt)
#pragma unroll
                for (int nt = 0; nt < 4; ++nt)
                    acc[mt][nt] = __builtin_amdgcn_mfma_f32_16x16x32_bf16(afc[mt], bfr[nt], acc[mt][nt], 0, 0, 0);
            if (kk < 15) {
#pragma unroll
                for (int mt = 0; mt < 4; ++mt)
                    afc[mt] = cvt8(buf[(kk + 1) & 1][mt][0], buf[(kk + 1) & 1][mt][1]);
            }
        }
    } else {
        short8 buf[2][4];
#pragma unroll
        for (int mt = 0; mt < 4; ++mt) {
            buf[0][mt] = *(const short8*)(Ab + abase[mt]);
            buf[1][mt] = *(const short8*)(Ab + abase[mt] + 32);
        }
#pragma unroll
        for (int mt = 0; mt < 4; ++mt) afc[mt] = buf[0][mt];
#pragma unroll
        for (int kk = 0; kk < 16; ++kk) {
            const int k0 = kk * 32;
            if (kk < 14) {
#pragma unroll
                for (int mt = 0; mt < 4; ++mt)
                    buf[kk & 1][mt] = *(const short8*)(Ab + abase[mt] + k0 + 64);
            }
            short8 bfr[4];
#pragma unroll
            for (int nt = 0; nt < 4; ++nt)
                bfr[nt] = *(const short8*)&Ws[(nt * 16 + l15) * 520 + k0 + lq * 8];
#pragma unroll
            for (int mt = 0; mt < 4; ++mt)
#pragma unroll
                for (int nt = 0; nt < 4; ++nt)
                    acc[mt][nt] = __builtin_amdgcn_mfma_f32_16x16x32_bf16(afc[mt], bfr[nt], acc[mt][nt], 0, 0, 0);
            if (kk < 15) {
#pragma unroll
                for (int mt = 0; mt < 4; ++mt) afc[mt] = buf[(kk + 1) & 1][mt];
            }
        }
    }

    // bias
    float bl[4];
#pragma unroll
    for (int nt = 0; nt < 4; ++nt) bl[nt] = bias[n0 + nt * 16 + l15];
#pragma unroll
    for (int mt = 0; mt < 4; ++mt)
#pragma unroll
        for (int nt = 0; nt < 4; ++nt)
#pragma unroll
            for (int r = 0; r < 4; ++r) acc[mt][nt][r] += bl[nt];

    if (EPI >= 1) {
        // softmax over the wave's 64 cols (one head), per output row
#pragma unroll
        for (int mt = 0; mt < 4; ++mt)
#pragma unroll
            for (int r = 0; r < 4; ++r) {
                float mx = fmaxf(fmaxf(acc[mt][0][r], acc[mt][1][r]),
                                 fmaxf(acc[mt][2][r], acc[mt][3][r]));
#pragma unroll
                for (int off = 1; off < 16; off <<= 1) mx = fmaxf(mx, __shfl_xor(mx, off));
                float s = 0.f;
#pragma unroll
                for (int nt = 0; nt < 4; ++nt) {
                    const float e = __expf(acc[mt][nt][r] - mx);
                    acc[mt][nt][r] = e; s += e;
                }
#pragma unroll
                for (int off = 1; off < 16; off <<= 1) s += __shfl_xor(s, off);
                const float inv = 1.f / s;
#pragma unroll
                for (int nt = 0; nt < 4; ++nt) acc[mt][nt][r] *= inv;
            }
    }
    if (EPI == 2) {
        const int bytemode = *maskmode;
#pragma unroll
        for (int mt = 0; mt < 4; ++mt)
#pragma unroll
            for (int r = 0; r < 4; ++r) {
                const int grow = m0w + mt * 16 + lq * 4 + r;
                const bool keep = bytemode ? (((const unsigned char*)mask)[grow] != 0)
                                           : (mask[grow] != 0);
                if (!keep) {
#pragma unroll
                    for (int nt = 0; nt < 4; ++nt) acc[mt][nt][r] = 0.f;
                }
            }
    }

    if (OUT == 2) {
        // transpose wave's 64x64 tile through LDS (reuse W region), store [d][s] rows
        __syncthreads();                 // everyone done reading Ws
        short* tw = Ws + wid * 4608;     // 64 x 72 shorts per wave
#pragma unroll
        for (int mt = 0; mt < 4; ++mt)
#pragma unroll
            for (int nt = 0; nt < 4; ++nt) {
                ushort4 p;
                p.x = f2bf(acc[mt][nt][0]); p.y = f2bf(acc[mt][nt][1]);
                p.z = f2bf(acc[mt][nt][2]); p.w = f2bf(acc[mt][nt][3]);
                *(ushort4*)&tw[(nt * 16 + l15) * 72 + mt * 16 + lq * 4] = p;
            }
        __syncthreads();
        const int b_idx  = m0w >> 12;          // SSEQ = 4096 rows per batch
        const int s_base = m0w & 4095;
        const int h = blockIdx.y;
        unsigned short* outp = (unsigned short*)Cv +
            ((size_t)(b_idx * NH + h) * 64 + lane) * SSEQ + s_base;
        const short* src = &tw[lane * 72];
#pragma unroll
        for (int sc = 0; sc < 8; ++sc)
            *(short8*)&outp[sc * 8] = *(const short8*)&src[sc * 8];
    } else {
#pragma unroll
        for (int mt = 0; mt < 4; ++mt)
#pragma unroll
            for (int r = 0; r < 4; ++r) {
                const size_t row = m0w + mt * 16 + lq * 4 + r;
#pragma unroll
                for (int nt = 0; nt < 4; ++nt) {
                    const int col = n0 + nt * 16 + l15;
                    if (OUT == 1)
                        ((unsigned short*)Cv)[row * D_MODEL + col] = f2bf(acc[mt][nt][r]);
                    else
                        ((float*)Cv)[row * D_MODEL + col] = acc[mt][nt][r];
                }
            }
    }
}

// kvT[e][d] += sum_s vT[e][s]*kT[d][s]; ksum[d] += sum_s kT[d][s].  MFMA, split-s.
__global__ __launch_bounds__(256)
void kv_accum_mfma(const unsigned short* __restrict__ kT, const unsigned short* __restrict__ vT,
                   float* __restrict__ kv, float* __restrict__ ksum, int i_idx)
{
    const int chunk = blockIdx.x;   // 0..7, 512 s each
    const int h = blockIdx.y, b = blockIdx.z;
    __shared__ short As[2048];
    __shared__ short Bs[2048];
    const int tid = threadIdx.x;
    const int wid = tid >> 6, lane = tid & 63;
    const int wm  = wid & 1,  wn  = wid >> 1;
    const int l15 = lane & 15, lq = lane >> 4;

    const size_t base = (size_t)(b * NH + h) * 64 * SSEQ + chunk * 512;
    const int srow = tid & 63, ssub = tid >> 6;
    const unsigned short* Ag = vT + base + (size_t)srow * SSEQ + ssub * 8;
    const unsigned short* Bg = kT + base + (size_t)srow * SSEQ + ssub * 8;
    short* AsW = As + wid * 512;
    short* BsW = Bs + wid * 512;

    floatx4 acc[2][2] = {};
    floatx4 ks[2] = {};
    short8 ones;
#pragma unroll
    for (int j = 0; j < 8; ++j) ones[j] = (short)0x3F80;

    const int aoff = (wm*32 + l15)*8;
    const int boff = (wn*32 + l15)*8;

    for (int k0 = 0; k0 < 512; k0 += 32) {
        __syncthreads();
        gld16(Ag + k0, AsW);
        gld16(Bg + k0, BsW);
        __syncthreads();
        short8 af[2], bfr[2];
#pragma unroll
        for (int mt = 0; mt < 2; ++mt) af[mt]  = *(const short8*)&As[lq*512 + aoff + mt*128];
#pragma unroll
        for (int nt = 0; nt < 2; ++nt) bfr[nt] = *(const short8*)&Bs[lq*512 + boff + nt*128];
#pragma unroll
        for (int mt = 0; mt < 2; ++mt)
#pragma unroll
            for (int nt = 0; nt < 2; ++nt)
                acc[mt][nt] = __builtin_amdgcn_mfma_f32_16x16x32_bf16(af[mt], bfr[nt], acc[mt][nt], 0, 0, 0);
        if (wm == 0) {
#pragma unroll
            for (int nt = 0; nt < 2; ++nt)
                ks[nt] = __builtin_amdgcn_mfma_f32_16x16x32_bf16(ones, bfr[nt], ks[nt], 0, 0, 0);
        }
    }
    float* kvb = kv + (size_t)((i_idx*B_ + b)*NH + h) * 4096;  // [e][d]
#pragma unroll
    for (int mt = 0; mt < 2; ++mt)
#pragma unroll
        for (int nt = 0; nt < 2; ++nt)
#pragma unroll
            for (int r = 0; r < 4; ++r) {
                const int e = wm*32 + mt*16 + lq*4 + r;
                const int d = wn*32 + nt*16 + l15;
                atomicAdd(&kvb[e*64 + d], acc[mt][nt][r]);
            }
    if (wm == 0 && lq == 0) {
        float* ksb = ksum + (size_t)((i_idx*B_ + b)*NH + h) * 64;
#pragma unroll
        for (int nt = 0; nt < 2; ++nt)
            atomicAdd(&ksb[wn*32 + nt*16 + l15], ks[nt][0]);
    }
}

// q2[row, h*64+e] = (q + sum_i (q@kv_i)*dinv_i)/3 ; q bf16, kvT bf16, MFMA
__global__ __launch_bounds__(256)
void combine_mfma(const unsigned short* __restrict__ Q, const unsigned short* __restrict__ kvT,
                  const float* __restrict__ ksum, unsigned short* __restrict__ Qo)
{
    const int m0 = blockIdx.x * 128;
    const int h  = blockIdx.y;
    const int b  = m0 >> 13;   // NSEQ = 8192
    __shared__ short qs[8192];
    __shared__ float skl[NUM_I][64];
    __shared__ float dinv[NUM_I][128];
    const int tid = threadIdx.x;
    const int wid = tid >> 6, lane = tid & 63;
    const int l15 = lane & 15, lq = lane >> 4;

    const unsigned short* Qbase = Q + (size_t)m0 * D_MODEL + h * 64;
#pragma unroll
    for (int j = 0; j < 4; ++j) {
        const int g = tid + j * 256;
        const int row = g & 127, c = g >> 7;
        gld16(Qbase + (size_t)row * D_MODEL + c * 8, qs + (size_t)(wid*64 + j*256) * 8);
    }
    if (tid < NUM_I * 64) {
        const int i = tid >> 6, d = tid & 63;
        skl[i][d] = ksum[(size_t)((i*B_ + b)*NH + h) * 64 + d];
    }
    __syncthreads();
    for (int it = tid; it < NUM_I * 128; it += 256) {
        const int i = it >> 7, row = it & 127;
        float s = 0.f;
#pragma unroll
        for (int d = 0; d < 64; ++d)
            s += bf2f((unsigned short)qs[(d >> 3)*1024 + row*8 + (d & 7)]) * skl[i][d];
        dinv[i][row] = 1.f / s;
    }
    __syncthreads();

    short8 af[2][2];
#pragma unroll
    for (int mt = 0; mt < 2; ++mt)
#pragma unroll
        for (int ks = 0; ks < 2; ++ks)
            af[mt][ks] = *(const short8*)&qs[(ks*4 + lq)*1024 + (wid*32 + mt*16 + l15)*8];

    floatx4 accO[2][4] = {};
    for (int i = 0; i < NUM_I; ++i) {
        const unsigned short* kvb = kvT + (size_t)((i*B_ + b)*NH + h) * 4096;  // [e][d]
        short8 bfr[4][2];
#pragma unroll
        for (int nt = 0; nt < 4; ++nt)
#pragma unroll
            for (int ks = 0; ks < 2; ++ks)
                bfr[nt][ks] = *(const short8*)&kvb[(nt*16 + l15)*64 + ks*32 + lq*8];
#pragma unroll
        for (int mt = 0; mt < 2; ++mt)
#pragma unroll
            for (int nt = 0; nt < 4; ++nt) {
                floatx4 p = {};
                p = __builtin_amdgcn_mfma_f32_16x16x32_bf16(af[mt][0], bfr[nt][0], p, 0, 0, 0);
                p = __builtin_amdgcn_mfma_f32_16x16x32_bf16(af[mt][1], bfr[nt][1], p, 0, 0, 0);
#pragma unroll
                for (int r = 0; r < 4; ++r) {
                    const int row = wid*32 + mt*16 + lq*4 + r;
                    accO[mt][nt][r] += p[r] * dinv[i][row];
                }
            }
    }
    const float inv3 = 1.f / 3.f;
#pragma unroll
    for (int mt = 0; mt < 2; ++mt)
#pragma unroll
        for (int nt = 0; nt < 4; ++nt)
#pragma unroll
            for (int r = 0; r < 4; ++r) {
                const int row = wid*32 + mt*16 + lq*4 + r;
                const int col = nt*16 + l15;
                const float qv = bf2f((unsigned short)qs[(col >> 3)*1024 + row*8 + (col & 7)]);
                Qo[(size_t)(m0 + row) * D_MODEL + h*64 + col] = f2bf((qv + accO[mt][nt][r]) * inv3);
            }
}

extern "C" void kernel_launch(void* const* d_in, const int* in_sizes, int n_in,
                              void* d_out, int out_size, void* d_ws, size_t ws_size,
                              hipStream_t stream)
{
    const float* x      = (const float*)d_in[0];
    const float* emb[3] = {(const float*)d_in[1], (const float*)d_in[2], (const float*)d_in[3]};
    const float* Wq = (const float*)d_in[4];
    const float* bq = (const float*)d_in[5];
    const float* Wk = (const float*)d_in[6];
    const float* bk = (const float*)d_in[7];
    const float* Wv = (const float*)d_in[8];
    const float* bv = (const float*)d_in[9];
    const float* Wo = (const float*)d_in[10];
    const float* bo = (const float*)d_in[11];
    const int* mask[3] = {(const int*)d_in[12], (const int*)d_in[13], (const int*)d_in[14]};
    float* out = (float*)d_out;

    float* ws = (float*)d_ws;
    unsigned short* qb   = (unsigned short*)(ws + Q_OFF);
    unsigned short* q2b  = (unsigned short*)(ws + Q2_OFF);
    unsigned short* kT   = (unsigned short*)(ws + KT_OFF);
    unsigned short* vT   = (unsigned short*)(ws + VT_OFF);
    unsigned short* wb   = (unsigned short*)(ws + WB_OFF);
    unsigned short* wqb  = wb;
    unsigned short* wkb  = wb + 262144;
    unsigned short* wvb  = wb + 1048576;
    unsigned short* wob  = wb + 1835008;
    float* kv   = ws + KV_OFF;
    float* ksum = ws + KS_OFF;
    unsigned short* kvb16 = (unsigned short*)(ws + KVB_OFF);
    int*   flag = (int*)(ws + FLAG_OFF);

    mask_mode_kernel<<<1, 256, 0, stream>>>(mask[0], flag);
    hipMemsetAsync(kv, 0, (size_t)(NUM_I*B_*NH*HD_*HD_ + NUM_I*B_*NH*HD_) * sizeof(float), stream);

    // weight conversions only (x/emb converted in-register inside proj2)
    f2bf_kernel<<<128, 256, 0, stream>>>(Wq, wqb, 32768);
    f2bf_kernel<<<384, 256, 0, stream>>>(Wk, wkb, 98304);
    f2bf_kernel<<<384, 256, 0, stream>>>(Wv, wvb, 98304);
    f2bf_kernel<<<128, 256, 0, stream>>>(Wo, wob, 32768);

    const dim3 gq(B_*NSEQ/256, NH);   // (128, 8)
    const dim3 gk(B_*SSEQ/256, NH);   // (64, 8)

    proj2<1, 1, true ><<<gq, 256, 0, stream>>>(x, wqb, bq, nullptr, nullptr, qb);
    for (int i = 0; i < NUM_I; ++i) {
        proj2<2, 2, true ><<<gk, 256, 0, stream>>>(emb[i], wkb + (size_t)i*262144,
                                                   bk + (size_t)i*D_MODEL, mask[i], flag, kT);
        proj2<0, 2, true ><<<gk, 256, 0, stream>>>(emb[i], wvb + (size_t)i*262144,
                                                   bv + (size_t)i*D_MODEL, nullptr, nullptr, vT);
        kv_accum_mfma<<<dim3(8, NH, B_), 256, 0, stream>>>(kT, vT, kv, ksum, i);
    }
    f2bf_kernel<<<192, 256, 0, stream>>>(kv, kvb16, 49152);
    combine_mfma<<<dim3(B_*NSEQ/128, NH), 256, 0, stream>>>(qb, kvb16, ksum, q2b);
    proj2<0, 0, false><<<gq, 256, 0, stream>>>(q2b, wob, bo, nullptr, nullptr, out);
}

// Round 5
// 573.410 us; speedup vs baseline: 1.1854x; 1.1854x over previous
//
#include <hip/hip_runtime.h>

#define D_MODEL 512
#define NH 8
#define HD_ 64
#define NUM_I 3
#define B_ 4
#define NSEQ 8192
#define SSEQ 4096

typedef __attribute__((ext_vector_type(8))) short short8;
typedef __attribute__((ext_vector_type(4))) float floatx4;

// workspace layout (float-element offsets)
static constexpr size_t Q_OFF    = 0;           // qb bf16 (8,388,608 float slots)
static constexpr size_t KT_OFF   = 8388608;     // kT bf16 (4,194,304); q2b aliases KT..VT
static constexpr size_t VT_OFF   = 12582912;    // vT bf16 (4,194,304)
static constexpr size_t Q2_OFF   = 8388608;     // q2b bf16 (written after last kv_accum read of kT/vT)
static constexpr size_t XB_OFF   = 16777216;    // xb bf16 (8,388,608); embb aliases (x dead after q-proj)
static constexpr size_t EMBB_OFF = 16777216;    // emb bf16 (4,194,304)
static constexpr size_t WB_OFF   = 25165824;    // weights bf16 (1,048,576)
static constexpr size_t KV_OFF   = 26214400;    // kv fp32 (393,216)
static constexpr size_t KS_OFF   = 26607616;    // ksum fp32 (6,144)
static constexpr size_t KVB_OFF  = 26613760;    // kv bf16 (98,304 float slots)
static constexpr size_t FLAG_OFF = 26712064;    // 1 int

__device__ __forceinline__ float bf2f(unsigned short u) {
    union { unsigned i; float f; } v; v.i = ((unsigned)u) << 16; return v.f;
}
__device__ __forceinline__ unsigned short f2bf(float f) {
    union { float f; unsigned i; } v; v.f = f;
    unsigned r = v.i + 0x7fffu + ((v.i >> 16) & 1u);
    return (unsigned short)(r >> 16);
}
__device__ __forceinline__ void gld16(const void* g, void* l) {
    __builtin_amdgcn_global_load_lds((const __attribute__((address_space(1))) void*)g,
                                     (__attribute__((address_space(3))) void*)l, 16, 0, 0);
}
__device__ __forceinline__ short8 cvt8(const float4& a, const float4& b) {
    short8 r;
    r[0] = (short)f2bf(a.x); r[1] = (short)f2bf(a.y);
    r[2] = (short)f2bf(a.z); r[3] = (short)f2bf(a.w);
    r[4] = (short)f2bf(b.x); r[5] = (short)f2bf(b.y);
    r[6] = (short)f2bf(b.z); r[7] = (short)f2bf(b.w);
    return r;
}

// Detect mask storage: int32 words (0/1) vs packed numpy bool bytes.
__global__ void mask_mode_kernel(const int* __restrict__ m, int* __restrict__ flag)
{
    __shared__ int any;
    if (threadIdx.x == 0) any = 0;
    __syncthreads();
    const unsigned v = (unsigned)m[threadIdx.x];
    if (v > 1u) atomicOr(&any, 1);
    __syncthreads();
    if (threadIdx.x == 0) *flag = any;
}

// fp32 -> bf16 pack, 8 elems/thread
__global__ __launch_bounds__(256)
void f2bf_kernel(const float* __restrict__ in, unsigned short* __restrict__ out, int n8)
{
    const int i = blockIdx.x * 256 + threadIdx.x;
    if (i >= n8) return;
    const float4 a = ((const float4*)in)[2*i];
    const float4 b = ((const float4*)in)[2*i + 1];
    ((short8*)out)[i] = cvt8(a, b);
}

// Weight-stationary barrier-free GEMM: C[m][n] = sum_k A[m][k]*W[n][k] + bias[n].
// Block: 64-col W strip (one head) XOR-swizzled in LDS (loaded once); 4 waves x 64 rows.
// A-frags (bf16, k-contiguous) direct from global, depth-6 register prefetch, no K-loop barriers.
// EPI: 0 none, 1 softmax per 64-col head, 2 softmax+row-mask.
// OUT: 0 fp32 row-major, 1 bf16 row-major, 2 bf16 transposed -> Cv[(b*NH+h)*64+d][SSEQ]
template<int EPI, int OUT>
__global__ __launch_bounds__(256, 2)
void proj3(const unsigned short* __restrict__ A, const unsigned short* __restrict__ W,
           const float* __restrict__ bias, const int* __restrict__ mask,
           const int* __restrict__ maskmode, void* __restrict__ Cv)
{
    __shared__ __align__(16) short Ws[32768];   // 64 cols x 64 granules(16B), swizzled
    const int tid = threadIdx.x;
    const int wid = tid >> 6, lane = tid & 63;
    const int l15 = lane & 15, lq = lane >> 4;
    const int m0w = blockIdx.x * 256 + wid * 64;
    const int n0  = blockIdx.y * 64;

    // stage W strip, swizzled: LDS slot col*64+i holds granule (i ^ (col&7)) of row col
#pragma unroll
    for (int j = 0; j < 16; ++j) {
        const int col = wid * 16 + j;
        gld16(W + (size_t)(n0 + col) * D_MODEL + ((lane ^ (col & 7)) << 3), Ws + col * 512);
    }
    __syncthreads();   // only barrier before epilogue

    floatx4 acc[4][4] = {};
    const unsigned short* Arow[4];
#pragma unroll
    for (int mt = 0; mt < 4; ++mt)
        Arow[mt] = A + (size_t)(m0w + mt * 16 + l15) * D_MODEL + lq * 8;

    short8 afb[6][4];
#pragma unroll
    for (int s = 0; s < 6; ++s)
#pragma unroll
        for (int mt = 0; mt < 4; ++mt)
            afb[s][mt] = *(const short8*)(Arow[mt] + s * 32);

    const int swz = l15 & 7;
#pragma unroll
    for (int ks = 0; ks < 16; ++ks) {
        const int slot = ks % 6;
        short8 bfr[4];
#pragma unroll
        for (int nt = 0; nt < 4; ++nt) {
            const int kg = (ks * 4 + lq) ^ swz;
            bfr[nt] = *(const short8*)&Ws[(nt * 16 + l15) * 512 + kg * 8];
        }
#pragma unroll
        for (int mt = 0; mt < 4; ++mt)
#pragma unroll
            for (int nt = 0; nt < 4; ++nt)
                acc[mt][nt] = __builtin_amdgcn_mfma_f32_16x16x32_bf16(afb[slot][mt], bfr[nt], acc[mt][nt], 0, 0, 0);
        if (ks < 10) {
#pragma unroll
            for (int mt = 0; mt < 4; ++mt)
                afb[slot][mt] = *(const short8*)(Arow[mt] + (ks + 6) * 32);
        }
    }

    // bias
    float bl[4];
#pragma unroll
    for (int nt = 0; nt < 4; ++nt) bl[nt] = bias[n0 + nt * 16 + l15];
#pragma unroll
    for (int mt = 0; mt < 4; ++mt)
#pragma unroll
        for (int nt = 0; nt < 4; ++nt)
#pragma unroll
            for (int r = 0; r < 4; ++r) acc[mt][nt][r] += bl[nt];

    if (EPI >= 1) {
        // softmax over the wave's 64 cols (one head), per output row
#pragma unroll
        for (int mt = 0; mt < 4; ++mt)
#pragma unroll
            for (int r = 0; r < 4; ++r) {
                float mx = fmaxf(fmaxf(acc[mt][0][r], acc[mt][1][r]),
                                 fmaxf(acc[mt][2][r], acc[mt][3][r]));
#pragma unroll
                for (int off = 1; off < 16; off <<= 1) mx = fmaxf(mx, __shfl_xor(mx, off));
                float s = 0.f;
#pragma unroll
                for (int nt = 0; nt < 4; ++nt) {
                    const float e = __expf(acc[mt][nt][r] - mx);
                    acc[mt][nt][r] = e; s += e;
                }
#pragma unroll
                for (int off = 1; off < 16; off <<= 1) s += __shfl_xor(s, off);
                const float inv = 1.f / s;
#pragma unroll
                for (int nt = 0; nt < 4; ++nt) acc[mt][nt][r] *= inv;
            }
    }
    if (EPI == 2) {
        const int bytemode = *maskmode;
#pragma unroll
        for (int mt = 0; mt < 4; ++mt)
#pragma unroll
            for (int r = 0; r < 4; ++r) {
                const int grow = m0w + mt * 16 + lq * 4 + r;
                const bool keep = bytemode ? (((const unsigned char*)mask)[grow] != 0)
                                           : (mask[grow] != 0);
                if (!keep) {
#pragma unroll
                    for (int nt = 0; nt < 4; ++nt) acc[mt][nt][r] = 0.f;
                }
            }
    }

    __syncthreads();   // all waves done reading Ws; reuse as transpose scratch (per-wave 16KB quarter)
    if (OUT == 2) {
        // per-wave buffer: [mt][col][s'] stride 24 shorts
        short* tw = Ws + wid * 8192;
#pragma unroll
        for (int mt = 0; mt < 4; ++mt)
#pragma unroll
            for (int nt = 0; nt < 4; ++nt) {
                ushort4 p;
                p.x = f2bf(acc[mt][nt][0]); p.y = f2bf(acc[mt][nt][1]);
                p.z = f2bf(acc[mt][nt][2]); p.w = f2bf(acc[mt][nt][3]);
                *(ushort4*)&tw[mt * 1536 + (nt * 16 + l15) * 24 + lq * 4] = p;
            }
        __syncthreads();
        const int b_idx  = m0w >> 12;          // SSEQ=4096 rows per batch
        const int s_base = m0w & 4095;
        unsigned short* outp = (unsigned short*)Cv +
            ((size_t)(b_idx * NH + blockIdx.y) * 64 + lane) * SSEQ + s_base;
#pragma unroll
        for (int mt = 0; mt < 4; ++mt) {
            const short8 p0 = *(const short8*)&tw[mt * 1536 + lane * 24];
            const short8 p1 = *(const short8*)&tw[mt * 1536 + lane * 24 + 8];
            *(short8*)&outp[mt * 16]     = p0;
            *(short8*)&outp[mt * 16 + 8] = p1;
        }
    } else if (OUT == 1) {
        // per-wave buffer: [mt][s'][col] stride 64 shorts -> contiguous row segments
        short* tw = Ws + wid * 8192;
#pragma unroll
        for (int mt = 0; mt < 4; ++mt)
#pragma unroll
            for (int nt = 0; nt < 4; ++nt)
#pragma unroll
                for (int r = 0; r < 4; ++r)
                    tw[mt * 1024 + (lq * 4 + r) * 64 + nt * 16 + l15] = (short)f2bf(acc[mt][nt][r]);
        __syncthreads();
        const int sp = lane >> 2, ch = lane & 3;
        unsigned short* Crow = (unsigned short*)Cv;
#pragma unroll
        for (int mt = 0; mt < 4; ++mt) {
            const size_t row = m0w + mt * 16 + sp;
            const short8 p0 = *(const short8*)&tw[mt * 1024 + sp * 64 + ch * 16];
            const short8 p1 = *(const short8*)&tw[mt * 1024 + sp * 64 + ch * 16 + 8];
            *(short8*)&Crow[row * D_MODEL + n0 + ch * 16]     = p0;
            *(short8*)&Crow[row * D_MODEL + n0 + ch * 16 + 8] = p1;
        }
    } else {
        // fp32 row-major: per-wave buffer [mt][s'][col] floats (4096 floats = 16KB quarter)
        float* twf = (float*)(Ws + wid * 8192);
#pragma unroll
        for (int mt = 0; mt < 4; ++mt)
#pragma unroll
            for (int nt = 0; nt < 4; ++nt)
#pragma unroll
                for (int r = 0; r < 4; ++r)
                    twf[mt * 1024 + (lq * 4 + r) * 64 + nt * 16 + l15] = acc[mt][nt][r];
        __syncthreads();
        const int sp = lane >> 2, ch = lane & 3;
        float* Crow = (float*)Cv;
#pragma unroll
        for (int mt = 0; mt < 4; ++mt) {
            const size_t row = m0w + mt * 16 + sp;
#pragma unroll
            for (int t = 0; t < 4; ++t) {
                const float4 p = *(const float4*)&twf[mt * 1024 + sp * 64 + ch * 16 + t * 4];
                *(float4*)&Crow[row * D_MODEL + n0 + ch * 16 + t * 4] = p;
            }
        }
    }
}

// kvT[e][d] += sum_s vT[e][s]*kT[d][s]; ksum[d] += sum_s kT[d][s].  MFMA, split-s.
__global__ __launch_bounds__(256)
void kv_accum_mfma(const unsigned short* __restrict__ kT, const unsigned short* __restrict__ vT,
                   float* __restrict__ kv, float* __restrict__ ksum, int i_idx)
{
    const int chunk = blockIdx.x;   // 0..7, 512 s each
    const int h = blockIdx.y, b = blockIdx.z;
    __shared__ short As[2048];
    __shared__ short Bs[2048];
    const int tid = threadIdx.x;
    const int wid = tid >> 6, lane = tid & 63;
    const int wm  = wid & 1,  wn  = wid >> 1;
    const int l15 = lane & 15, lq = lane >> 4;

    const size_t base = (size_t)(b * NH + h) * 64 * SSEQ + chunk * 512;
    const int srow = tid & 63, ssub = tid >> 6;
    const unsigned short* Ag = vT + base + (size_t)srow * SSEQ + ssub * 8;
    const unsigned short* Bg = kT + base + (size_t)srow * SSEQ + ssub * 8;
    short* AsW = As + wid * 512;
    short* BsW = Bs + wid * 512;

    floatx4 acc[2][2] = {};
    floatx4 ks[2] = {};
    short8 ones;
#pragma unroll
    for (int j = 0; j < 8; ++j) ones[j] = (short)0x3F80;

    const int aoff = (wm*32 + l15)*8;
    const int boff = (wn*32 + l15)*8;

    for (int k0 = 0; k0 < 512; k0 += 32) {
        __syncthreads();
        gld16(Ag + k0, AsW);
        gld16(Bg + k0, BsW);
        __syncthreads();
        short8 af[2], bfr[2];
#pragma unroll
        for (int mt = 0; mt < 2; ++mt) af[mt]  = *(const short8*)&As[lq*512 + aoff + mt*128];
#pragma unroll
        for (int nt = 0; nt < 2; ++nt) bfr[nt] = *(const short8*)&Bs[lq*512 + boff + nt*128];
#pragma unroll
        for (int mt = 0; mt < 2; ++mt)
#pragma unroll
            for (int nt = 0; nt < 2; ++nt)
                acc[mt][nt] = __builtin_amdgcn_mfma_f32_16x16x32_bf16(af[mt], bfr[nt], acc[mt][nt], 0, 0, 0);
        if (wm == 0) {
#pragma unroll
            for (int nt = 0; nt < 2; ++nt)
                ks[nt] = __builtin_amdgcn_mfma_f32_16x16x32_bf16(ones, bfr[nt], ks[nt], 0, 0, 0);
        }
    }
    float* kvb = kv + (size_t)((i_idx*B_ + b)*NH + h) * 4096;  // [e][d]
#pragma unroll
    for (int mt = 0; mt < 2; ++mt)
#pragma unroll
        for (int nt = 0; nt < 2; ++nt)
#pragma unroll
            for (int r = 0; r < 4; ++r) {
                const int e = wm*32 + mt*16 + lq*4 + r;
                const int d = wn*32 + nt*16 + l15;
                atomicAdd(&kvb[e*64 + d], acc[mt][nt][r]);
            }
    if (wm == 0 && lq == 0) {
        float* ksb = ksum + (size_t)((i_idx*B_ + b)*NH + h) * 64;
#pragma unroll
        for (int nt = 0; nt < 2; ++nt)
            atomicAdd(&ksb[wn*32 + nt*16 + l15], ks[nt][0]);
    }
}

// q2[row, h*64+e] = (q + sum_i (q@kv_i)*dinv_i)/3 ; q bf16, kvT bf16, MFMA
__global__ __launch_bounds__(256)
void combine_mfma(const unsigned short* __restrict__ Q, const unsigned short* __restrict__ kvT,
                  const float* __restrict__ ksum, unsigned short* __restrict__ Qo)
{
    const int m0 = blockIdx.x * 128;
    const int h  = blockIdx.y;
    const int b  = m0 >> 13;   // NSEQ = 8192
    __shared__ short qs[8192];
    __shared__ float skl[NUM_I][64];
    __shared__ float dinv[NUM_I][128];
    const int tid = threadIdx.x;
    const int wid = tid >> 6, lane = tid & 63;
    const int l15 = lane & 15, lq = lane >> 4;

    const unsigned short* Qbase = Q + (size_t)m0 * D_MODEL + h * 64;
#pragma unroll
    for (int j = 0; j < 4; ++j) {
        const int g = tid + j * 256;
        const int row = g & 127, c = g >> 7;
        gld16(Qbase + (size_t)row * D_MODEL + c * 8, qs + (size_t)(wid*64 + j*256) * 8);
    }
    if (tid < NUM_I * 64) {
        const int i = tid >> 6, d = tid & 63;
        skl[i][d] = ksum[(size_t)((i*B_ + b)*NH + h) * 64 + d];
    }
    __syncthreads();
    for (int it = tid; it < NUM_I * 128; it += 256) {
        const int i = it >> 7, row = it & 127;
        float s = 0.f;
#pragma unroll
        for (int d = 0; d < 64; ++d)
            s += bf2f((unsigned short)qs[(d >> 3)*1024 + row*8 + (d & 7)]) * skl[i][d];
        dinv[i][row] = 1.f / s;
    }
    __syncthreads();

    short8 af[2][2];
#pragma unroll
    for (int mt = 0; mt < 2; ++mt)
#pragma unroll
        for (int ks = 0; ks < 2; ++ks)
            af[mt][ks] = *(const short8*)&qs[(ks*4 + lq)*1024 + (wid*32 + mt*16 + l15)*8];

    floatx4 accO[2][4] = {};
    for (int i = 0; i < NUM_I; ++i) {
        const unsigned short* kvb = kvT + (size_t)((i*B_ + b)*NH + h) * 4096;  // [e][d]
        short8 bfr[4][2];
#pragma unroll
        for (int nt = 0; nt < 4; ++nt)
#pragma unroll
            for (int ks = 0; ks < 2; ++ks)
                bfr[nt][ks] = *(const short8*)&kvb[(nt*16 + l15)*64 + ks*32 + lq*8];
#pragma unroll
        for (int mt = 0; mt < 2; ++mt)
#pragma unroll
            for (int nt = 0; nt < 4; ++nt) {
                floatx4 p = {};
                p = __builtin_amdgcn_mfma_f32_16x16x32_bf16(af[mt][0], bfr[nt][0], p, 0, 0, 0);
                p = __builtin_amdgcn_mfma_f32_16x16x32_bf16(af[mt][1], bfr[nt][1], p, 0, 0, 0);
#pragma unroll
                for (int r = 0; r < 4; ++r) {
                    const int row = wid*32 + mt*16 + lq*4 + r;
                    accO[mt][nt][r] += p[r] * dinv[i][row];
                }
            }
    }
    const float inv3 = 1.f / 3.f;
#pragma unroll
    for (int mt = 0; mt < 2; ++mt)
#pragma unroll
        for (int nt = 0; nt < 4; ++nt)
#pragma unroll
            for (int r = 0; r < 4; ++r) {
                const int row = wid*32 + mt*16 + lq*4 + r;
                const int col = nt*16 + l15;
                const float qv = bf2f((unsigned short)qs[(col >> 3)*1024 + row*8 + (col & 7)]);
                Qo[(size_t)(m0 + row) * D_MODEL + h*64 + col] = f2bf((qv + accO[mt][nt][r]) * inv3);
            }
}

extern "C" void kernel_launch(void* const* d_in, const int* in_sizes, int n_in,
                              void* d_out, int out_size, void* d_ws, size_t ws_size,
                              hipStream_t stream)
{
    const float* x      = (const float*)d_in[0];
    const float* emb[3] = {(const float*)d_in[1], (const float*)d_in[2], (const float*)d_in[3]};
    const float* Wq = (const float*)d_in[4];
    const float* bq = (const float*)d_in[5];
    const float* Wk = (const float*)d_in[6];
    const float* bk = (const float*)d_in[7];
    const float* Wv = (const float*)d_in[8];
    const float* bv = (const float*)d_in[9];
    const float* Wo = (const float*)d_in[10];
    const float* bo = (const float*)d_in[11];
    const int* mask[3] = {(const int*)d_in[12], (const int*)d_in[13], (const int*)d_in[14]};
    float* out = (float*)d_out;

    float* ws = (float*)d_ws;
    unsigned short* qb   = (unsigned short*)(ws + Q_OFF);
    unsigned short* kT   = (unsigned short*)(ws + KT_OFF);
    unsigned short* vT   = (unsigned short*)(ws + VT_OFF);
    unsigned short* q2b  = (unsigned short*)(ws + Q2_OFF);
    unsigned short* xb   = (unsigned short*)(ws + XB_OFF);
    unsigned short* embb = (unsigned short*)(ws + EMBB_OFF);
    unsigned short* wb   = (unsigned short*)(ws + WB_OFF);
    unsigned short* wqb  = wb;
    unsigned short* wkb  = wb + 262144;
    unsigned short* wvb  = wb + 1048576;
    unsigned short* wob  = wb + 1835008;
    float* kv   = ws + KV_OFF;
    float* ksum = ws + KS_OFF;
    unsigned short* kvb16 = (unsigned short*)(ws + KVB_OFF);
    int*   flag = (int*)(ws + FLAG_OFF);

    mask_mode_kernel<<<1, 256, 0, stream>>>(mask[0], flag);
    hipMemsetAsync(kv, 0, (size_t)(NUM_I*B_*NH*HD_*HD_ + NUM_I*B_*NH*HD_) * sizeof(float), stream);

    f2bf_kernel<<<128,  256, 0, stream>>>(Wq, wqb, 32768);
    f2bf_kernel<<<384,  256, 0, stream>>>(Wk, wkb, 98304);
    f2bf_kernel<<<384,  256, 0, stream>>>(Wv, wvb, 98304);
    f2bf_kernel<<<128,  256, 0, stream>>>(Wo, wob, 32768);
    f2bf_kernel<<<8192, 256, 0, stream>>>(x,  xb,  2097152);

    const dim3 gq(B_*NSEQ/256, NH);   // (128, 8)
    const dim3 gk(B_*SSEQ/256, NH);   // (64, 8)

    proj3<1, 1><<<gq, 256, 0, stream>>>(xb, wqb, bq, nullptr, nullptr, qb);
    for (int i = 0; i < NUM_I; ++i) {
        f2bf_kernel<<<4096, 256, 0, stream>>>(emb[i], embb, 1048576);
        proj3<2, 2><<<gk, 256, 0, stream>>>(embb, wkb + (size_t)i*262144,
                                            bk + (size_t)i*D_MODEL, mask[i], flag, kT);
        proj3<0, 2><<<gk, 256, 0, stream>>>(embb, wvb + (size_t)i*262144,
                                            bv + (size_t)i*D_MODEL, nullptr, nullptr, vT);
        kv_accum_mfma<<<dim3(8, NH, B_), 256, 0, stream>>>(kT, vT, kv, ksum, i);
    }
    f2bf_kernel<<<192, 256, 0, stream>>>(kv, kvb16, 49152);
    combine_mfma<<<dim3(B_*NSEQ/128, NH), 256, 0, stream>>>(qb, kvb16, ksum, q2b);
    proj3<0, 0><<<gq, 256, 0, stream>>>(q2b, wob, bo, nullptr, nullptr, out);
}